// Round 6
// baseline (814.620 us; speedup 1.0000x reference)
//
#include <hip/hip_runtime.h>
#include <cstdint>

#define NN  50000
#define MD  64
#define HD  128
#define RR  4
#define FD  7
#define EE  800000
#define BG  32
#define NMX 512
#define NPASS 4                   // h-slices of 32 cols (64 B)
#define GNB3 ((NN + 63) / 64)     // 782 blocks per gather pass (64 nodes/block)

typedef __attribute__((ext_vector_type(8))) short bf16x8;
typedef __attribute__((ext_vector_type(4))) float f32x4;

__device__ __forceinline__ unsigned short f2bf(float f) {
    unsigned u = __builtin_bit_cast(unsigned, f);
    u = (u + 0x7fffu + ((u >> 16) & 1u)) >> 16;
    return (unsigned short)u;
}
__device__ __forceinline__ float bflo(unsigned u) { return __builtin_bit_cast(float, u << 16); }
__device__ __forceinline__ float bfhi(unsigned u) { return __builtin_bit_cast(float, u & 0xffff0000u); }

__device__ __forceinline__ bf16x8 pack8(float4 a, float4 b) {
    bf16x8 r;
    r[0]=(short)f2bf(a.x); r[1]=(short)f2bf(a.y); r[2]=(short)f2bf(a.z); r[3]=(short)f2bf(a.w);
    r[4]=(short)f2bf(b.x); r[5]=(short)f2bf(b.y); r[6]=(short)f2bf(b.z); r[7]=(short)f2bf(b.w);
    return r;
}

// ---------------------------------------------------------------------------
// Edge logits via bf16 MFMA: C = Z Z^T + bias. 64x64 tile / 256-block.
// ---------------------------------------------------------------------------
__global__ __launch_bounds__(256) void edge_kernel(const unsigned short* __restrict__ zdb,
                                                   const float* __restrict__ bias,
                                                   float* __restrict__ out) {
    __shared__ float cstage[64][68];
    const int b  = blockIdx.z;
    const int tn = blockIdx.y * 64;
    const int tk = blockIdx.x * 64;
    const unsigned short* zb = zdb + (size_t)b * NMX * MD;
    const int tid = threadIdx.x, wave = tid >> 6, lane = tid & 63;
    const int l15 = lane & 15, k8 = (lane >> 4) * 8;

    const unsigned short* ap = zb + (size_t)(tn + wave * 16 + l15) * MD + k8;
    bf16x8 af0 = *(const bf16x8*)ap;
    bf16x8 af1 = *(const bf16x8*)(ap + 32);

    f32x4 acc[4];
    #pragma unroll
    for (int ct = 0; ct < 4; ct++) acc[ct] = (f32x4){0.f, 0.f, 0.f, 0.f};
    const unsigned short* bp = zb + (size_t)(tk + l15) * MD + k8;
    #pragma unroll
    for (int ct = 0; ct < 4; ct++) {
        bf16x8 b0 = *(const bf16x8*)(bp + (size_t)ct * 16 * MD);
        bf16x8 b1 = *(const bf16x8*)(bp + (size_t)ct * 16 * MD + 32);
        acc[ct] = __builtin_amdgcn_mfma_f32_16x16x32_bf16(af0, b0, acc[ct], 0, 0, 0);
        acc[ct] = __builtin_amdgcn_mfma_f32_16x16x32_bf16(af1, b1, acc[ct], 0, 0, 0);
    }
    #pragma unroll
    for (int ct = 0; ct < 4; ct++)
        #pragma unroll
        for (int i = 0; i < 4; i++)
            cstage[wave * 16 + (lane >> 4) * 4 + i][ct * 16 + l15] = acc[ct][i];
    __syncthreads();
    const float bi = bias[0];
    #pragma unroll
    for (int it = 0; it < 4; it++) {
        int f = tid + it * 256;
        int row = f >> 4, c4 = (f & 15) * 4;
        float4 v = *(const float4*)&cstage[row][c4];
        v.x += bi; v.y += bi; v.z += bi; v.w += bi;
        *(float4*)(out + ((size_t)b * NMX + tn + row) * NMX + tk + c4) = v;
    }
}

// ---------------------------------------------------------------------------
// Converters
// ---------------------------------------------------------------------------
__global__ __launch_bounds__(256) void cvt_kernel(const float* __restrict__ src,
                                                  unsigned short* __restrict__ dst,
                                                  int n4) {
    int i = blockIdx.x * 256 + threadIdx.x;
    if (i >= n4) return;
    float4 v = *(const float4*)(src + (size_t)i * 4);
    ushort4 o = {f2bf(v.x), f2bf(v.y), f2bf(v.z), f2bf(v.w)};
    *(ushort4*)(dst + (size_t)i * 4) = o;
}

__global__ __launch_bounds__(256) void tcvt_kernel(const float* __restrict__ src,
                                                   unsigned short* __restrict__ dst,
                                                   int K, int H) {
    int r = blockIdx.y;
    int i = blockIdx.x * 256 + threadIdx.x;
    if (i >= K * H) return;
    int k = i / H, h = i % H;
    float v = src[(size_t)r * K * H + i];
    dst[(size_t)r * K * H + (size_t)h * K + k] = f2bf(v);
}

// ---------------------------------------------------------------------------
// Fused MLP (two MFMA stages)
// ---------------------------------------------------------------------------
template <int K1, int MODE, bool BLK>
__global__ __launch_bounds__(256) void fused_kernel(
    const unsigned short* __restrict__ in,
    const unsigned short* __restrict__ Wt1,
    const float* __restrict__ b1,
    float* __restrict__ state,
    const unsigned short* __restrict__ Wt2,
    const float* __restrict__ b2,
    unsigned short* __restrict__ msgb,
    const float* __restrict__ Wout,
    const float* __restrict__ bout,
    float* __restrict__ node_out,
    int nrows)
{
    constexpr int KC1 = K1 / 32;
    __shared__ float cstage[64][132];
    __shared__ float sWout[MODE == 2 ? HD * FD : 1];
    const int tid = threadIdx.x, wave = tid >> 6, lane = tid & 63;
    const int l15 = lane & 15, k8 = (lane >> 4) * 8;
    const int rbase = blockIdx.x * 64;

    if constexpr (MODE == 2)
        for (int i = tid; i < HD * FD; i += 256) sWout[i] = Wout[i];

    // ---- stage 1 MFMA ----
    int rclamp = min(rbase + wave * 16 + l15, nrows - 1);
    bf16x8 af[KC1];
    #pragma unroll
    for (int c = 0; c < KC1; c++) {
        size_t off = BLK ? ((size_t)c * NN * 32 + (size_t)rclamp * 32 + k8)
                         : ((size_t)rclamp * K1 + (size_t)c * 32 + k8);
        af[c] = *(const bf16x8*)(in + off);
    }
    f32x4 acc[8];
    #pragma unroll
    for (int ct = 0; ct < 8; ct++) acc[ct] = (f32x4){0.f, 0.f, 0.f, 0.f};
    const unsigned short* bp = Wt1 + (size_t)l15 * K1 + k8;
    #pragma unroll
    for (int ct = 0; ct < 8; ct++)
        #pragma unroll
        for (int c = 0; c < KC1; c++) {
            bf16x8 bf = *(const bf16x8*)(bp + (size_t)ct * 16 * K1 + c * 32);
            acc[ct] = __builtin_amdgcn_mfma_f32_16x16x32_bf16(af[c], bf, acc[ct], 0, 0, 0);
        }
    #pragma unroll
    for (int ct = 0; ct < 8; ct++)
        #pragma unroll
        for (int i = 0; i < 4; i++)
            cstage[wave * 16 + (lane >> 4) * 4 + i][ct * 16 + l15] = acc[ct][i];
    __syncthreads();

    // ---- epilogue 1: bias+relu (+state_old) -> state_new ----
    #pragma unroll
    for (int it = 0; it < 8; it++) {
        int f = tid + it * 256;
        int row = f >> 5, c4 = (f & 31) * 4;
        int grow = rbase + row;
        if (grow < nrows) {
            float4 v = *(const float4*)&cstage[row][c4];
            float4 bb = *(const float4*)(b1 + c4);
            v.x = fmaxf(v.x + bb.x, 0.f);
            v.y = fmaxf(v.y + bb.y, 0.f);
            v.z = fmaxf(v.z + bb.z, 0.f);
            v.w = fmaxf(v.w + bb.w, 0.f);
            if constexpr (MODE >= 1) {
                float4 so = *(const float4*)(state + (size_t)grow * HD + c4);
                v.x += so.x; v.y += so.y; v.z += so.z; v.w += so.w;
            }
            if constexpr (MODE <= 1)
                *(float4*)(state + (size_t)grow * HD + c4) = v;
            *(float4*)&cstage[row][c4] = v;
        }
    }
    __syncthreads();

    if constexpr (MODE <= 1) {
        // ---- stage 2 MFMA: A-frags from updated cstage ----
        bf16x8 af2[4];
        #pragma unroll
        for (int c = 0; c < 4; c++) {
            float4 u0 = *(const float4*)&cstage[wave * 16 + l15][c * 32 + k8];
            float4 u1 = *(const float4*)&cstage[wave * 16 + l15][c * 32 + k8 + 4];
            af2[c] = pack8(u0, u1);
        }
        f32x4 acc2[8];
        #pragma unroll
        for (int ct = 0; ct < 8; ct++) acc2[ct] = (f32x4){0.f, 0.f, 0.f, 0.f};
        const unsigned short* bp2 = Wt2 + (size_t)l15 * HD + k8;
        #pragma unroll
        for (int ct = 0; ct < 8; ct++)
            #pragma unroll
            for (int c = 0; c < 4; c++) {
                bf16x8 bf = *(const bf16x8*)(bp2 + (size_t)ct * 16 * HD + c * 32);
                acc2[ct] = __builtin_amdgcn_mfma_f32_16x16x32_bf16(af2[c], bf, acc2[ct], 0, 0, 0);
            }
        __syncthreads();
        #pragma unroll
        for (int ct = 0; ct < 8; ct++)
            #pragma unroll
            for (int i = 0; i < 4; i++)
                cstage[wave * 16 + (lane >> 4) * 4 + i][ct * 16 + l15] = acc2[ct][i];
        __syncthreads();
        #pragma unroll
        for (int it = 0; it < 8; it++) {
            int f = tid + it * 256;
            int row = f >> 5, c4 = (f & 31) * 4;
            int grow = rbase + row;
            if (grow < nrows) {
                float4 v = *(const float4*)&cstage[row][c4];
                float4 bb = *(const float4*)(b2 + c4);
                v.x = fmaxf(v.x + bb.x, 0.f);
                v.y = fmaxf(v.y + bb.y, 0.f);
                v.z = fmaxf(v.z + bb.z, 0.f);
                v.w = fmaxf(v.w + bb.w, 0.f);
                ushort4 o = {f2bf(v.x), f2bf(v.y), f2bf(v.z), f2bf(v.w)};
                size_t off = (size_t)(c4 >> 5) * NN * 32 + (size_t)grow * 32 + (c4 & 31);
                *(ushort4*)(msgb + off) = o;
            }
        }
    } else {
        // ---- out projection: 64 rows x 7 cols, strided over 256 threads ----
        for (int i = tid; i < 64 * FD; i += 256) {
            int row = i / FD, ff = i - row * FD;
            int grow = rbase + row;
            if (grow < nrows) {
                float a = bout[ff];
                #pragma unroll 8
                for (int k = 0; k < HD; k++)
                    a += cstage[row][k] * sWout[k * FD + ff];
                node_out[(size_t)grow * FD + ff] = a;
            }
        }
    }
}

// ---------------------------------------------------------------------------
// CSR build
// ---------------------------------------------------------------------------
__global__ __launch_bounds__(256) void hist_kernel(const int* __restrict__ dst,
                                                   int* __restrict__ cnt) {
    int e = blockIdx.x * 256 + threadIdx.x;
    if (e < EE) atomicAdd(&cnt[dst[e]], 1);
}

__global__ __launch_bounds__(256) void scan1_kernel(const int* __restrict__ cnt,
                                                    int* __restrict__ incl,
                                                    int* __restrict__ bsum) {
    __shared__ int s[256];
    int i = blockIdx.x * 256 + threadIdx.x;
    int t = threadIdx.x;
    s[t] = (i < NN) ? cnt[i] : 0;
    __syncthreads();
    #pragma unroll
    for (int off = 1; off < 256; off <<= 1) {
        int x = (t >= off) ? s[t - off] : 0;
        __syncthreads();
        s[t] += x;
        __syncthreads();
    }
    if (i < NN) incl[i] = s[t];
    if (t == 255) bsum[blockIdx.x] = s[255];
}

__global__ __launch_bounds__(256) void scan2_kernel(int* __restrict__ bsum, int nb) {
    __shared__ int s[256];
    int t = threadIdx.x;
    int orig = (t < nb) ? bsum[t] : 0;
    s[t] = orig;
    __syncthreads();
    #pragma unroll
    for (int off = 1; off < 256; off <<= 1) {
        int x = (t >= off) ? s[t - off] : 0;
        __syncthreads();
        s[t] += x;
        __syncthreads();
    }
    if (t < nb) bsum[t] = s[t] - orig;
}

__global__ __launch_bounds__(256) void scan3_kernel(const int* __restrict__ cnt,
                                                    const int* __restrict__ incl,
                                                    const int* __restrict__ bsum,
                                                    int* __restrict__ row_ptr,
                                                    int* __restrict__ cursor) {
    int i = blockIdx.x * 256 + threadIdx.x;
    if (i < NN) {
        int ex = incl[i] - cnt[i] + bsum[blockIdx.x];
        row_ptr[i] = ex;
        cursor[i]  = ex;
        if (i == 0) row_ptr[NN] = EE;
    }
}

__global__ __launch_bounds__(256) void bucket_kernel(const int* __restrict__ src,
                                                     const int* __restrict__ dst,
                                                     int* __restrict__ cursor,
                                                     int* __restrict__ colsrc) {
    int e = blockIdx.x * 256 + threadIdx.x;
    if (e < EE) {
        int pos = atomicAdd(&cursor[dst[e]], 1);
        colsrc[pos] = src[e];
    }
}

// ---------------------------------------------------------------------------
// Degree-ordered node schedule: counting sort into 64 degree bins.
// ---------------------------------------------------------------------------
__global__ __launch_bounds__(256) void dhist_kernel(const int* __restrict__ rp,
                                                    int* __restrict__ dbin) {
    int i = blockIdx.x * 256 + threadIdx.x;
    if (i < NN) {
        int d = min(rp[i + 1] - rp[i], 63);
        atomicAdd(&dbin[d], 1);
    }
}

__global__ __launch_bounds__(64) void dscan_kernel(const int* __restrict__ dbin,
                                                   int* __restrict__ dcur) {
    __shared__ int s[64];
    int t = threadIdx.x;
    int x = dbin[t];
    s[t] = x;
    __syncthreads();
    #pragma unroll
    for (int off = 1; off < 64; off <<= 1) {
        int y = (t >= off) ? s[t - off] : 0;
        __syncthreads();
        s[t] += y;
        __syncthreads();
    }
    dcur[t] = s[t] - x;   // exclusive
}

__global__ __launch_bounds__(256) void dscatter_kernel(const int* __restrict__ rp,
                                                       int* __restrict__ dcur,
                                                       int* __restrict__ order) {
    int i = blockIdx.x * 256 + threadIdx.x;
    if (i < NN) {
        int d = min(rp[i + 1] - rp[i], 63);
        int pos = atomicAdd(&dcur[d], 1);
        order[pos] = i;
    }
}

// ---------------------------------------------------------------------------
// Gather v3: 4 lanes/node x 16B (dwordx4), 16 nodes/wave, degree-ordered.
// msg/agg layout: [pass][node][32 bf16] (64 B rows), viewed as uint4.
// ---------------------------------------------------------------------------
__global__ __launch_bounds__(256) void gather_kernel(const int* __restrict__ rp,
                                                     const int* __restrict__ order,
                                                     const int* __restrict__ colsrc,
                                                     const uint4* __restrict__ msg4,
                                                     uint4* __restrict__ agg4) {
    int pass = blockIdx.x / GNB3;
    int nb   = blockIdx.x - pass * GNB3;
    int idx  = nb * 64 + (threadIdx.x >> 2);
    int l    = threadIdx.x & 3;
    if (idx >= NN) return;
    int v = order[idx];
    int beg = rp[v], end = rp[v + 1];
    const uint4* base = msg4 + (size_t)pass * NN * 4 + l;
    float a[8], b[8];
    #pragma unroll
    for (int q = 0; q < 8; q++) { a[q] = 0.f; b[q] = 0.f; }
    int j = beg;
    for (; j + 1 < end; j += 2) {
        uint4 u = base[(size_t)colsrc[j]     * 4];
        uint4 w = base[(size_t)colsrc[j + 1] * 4];
        a[0] += bflo(u.x); a[1] += bfhi(u.x);
        a[2] += bflo(u.y); a[3] += bfhi(u.y);
        a[4] += bflo(u.z); a[5] += bfhi(u.z);
        a[6] += bflo(u.w); a[7] += bfhi(u.w);
        b[0] += bflo(w.x); b[1] += bfhi(w.x);
        b[2] += bflo(w.y); b[3] += bfhi(w.y);
        b[4] += bflo(w.z); b[5] += bfhi(w.z);
        b[6] += bflo(w.w); b[7] += bfhi(w.w);
    }
    if (j < end) {
        uint4 u = base[(size_t)colsrc[j] * 4];
        a[0] += bflo(u.x); a[1] += bfhi(u.x);
        a[2] += bflo(u.y); a[3] += bfhi(u.y);
        a[4] += bflo(u.z); a[5] += bfhi(u.z);
        a[6] += bflo(u.w); a[7] += bfhi(u.w);
    }
    uint4 o;
    o.x = (unsigned)f2bf(a[0] + b[0]) | ((unsigned)f2bf(a[1] + b[1]) << 16);
    o.y = (unsigned)f2bf(a[2] + b[2]) | ((unsigned)f2bf(a[3] + b[3]) << 16);
    o.z = (unsigned)f2bf(a[4] + b[4]) | ((unsigned)f2bf(a[5] + b[5]) << 16);
    o.w = (unsigned)f2bf(a[6] + b[6]) | ((unsigned)f2bf(a[7] + b[7]) << 16);
    agg4[(size_t)pass * NN * 4 + (size_t)v * 4 + l] = o;
}

extern "C" void kernel_launch(void* const* d_in, const int* in_sizes, int n_in,
                              void* d_out, int out_size, void* d_ws, size_t ws_size,
                              hipStream_t stream) {
    const float* z          = (const float*)d_in[0];
    const int*   edge_index = (const int*)  d_in[1];
    const float* z_dense    = (const float*)d_in[2];
    const float* bias       = (const float*)d_in[3];
    const float* W_in       = (const float*)d_in[4];
    const float* b_in       = (const float*)d_in[5];
    const float* W_msg      = (const float*)d_in[6];
    const float* b_msg      = (const float*)d_in[7];
    const float* W_upd      = (const float*)d_in[8];
    const float* b_upd      = (const float*)d_in[9];
    const float* W_out      = (const float*)d_in[10];
    const float* b_out      = (const float*)d_in[11];

    float* out      = (float*)d_out;
    float* edge_out = out;
    float* node_out = out + (size_t)BG * NMX * NMX;

    // ---- workspace ----
    char* p = (char*)d_ws;
    float* state = (float*)p;                     p += (size_t)NN * HD * 4;
    unsigned short* msgb   = (unsigned short*)p;  p += (size_t)NN * HD * 2;  // [4][NN][32]
    unsigned short* aggb   = (unsigned short*)p;  p += (size_t)NN * HD * 2;  // [4][NN][32]
    unsigned short* zb     = (unsigned short*)p;  p += (size_t)NN * MD * 2;
    unsigned short* zdb    = (unsigned short*)p;  p += (size_t)BG * NMX * MD * 2;
    unsigned short* wt_in  = (unsigned short*)p;  p += (size_t)HD * MD * 2;
    unsigned short* wt_msg = (unsigned short*)p;  p += (size_t)RR * HD * HD * 2;
    unsigned short* wt_upd = (unsigned short*)p;  p += (size_t)RR * HD * HD * 2;
    int* cnt     = (int*)p;                       p += (size_t)NN * 4;
    int* incl    = (int*)p;                       p += (size_t)NN * 4;
    int* row_ptr = (int*)p;                       p += (size_t)(NN + 1) * 4;
    int* colsrc  = (int*)p;                       p += (size_t)EE * 4;
    int* order   = (int*)p;                       p += (size_t)NN * 4;
    int* bsum    = (int*)p;                       p += 256 * 4;
    int* dbin    = (int*)p;                       p += 64 * 4;
    int* dcur    = (int*)p;

    const int* src = edge_index;
    const int* dst = edge_index + EE;
    const int NB = (NN + 255) / 256;
    const int EB = (EE + 255) / 256;

    // ---- edge path ----
    cvt_kernel<<<(BG * NMX * MD / 4 + 255) / 256, 256, 0, stream>>>(
        z_dense, zdb, BG * NMX * MD / 4);
    dim3 eg(NMX / 64, NMX / 64, BG);
    edge_kernel<<<eg, 256, 0, stream>>>(zdb, bias, edge_out);

    // ---- conversions ----
    cvt_kernel<<<(NN * MD / 4 + 255) / 256, 256, 0, stream>>>(z, zb, NN * MD / 4);
    tcvt_kernel<<<dim3((MD * HD + 255) / 256, 1), 256, 0, stream>>>(W_in, wt_in, MD, HD);
    tcvt_kernel<<<dim3((HD * HD + 255) / 256, RR), 256, 0, stream>>>(W_msg, wt_msg, HD, HD);
    tcvt_kernel<<<dim3((HD * HD + 255) / 256, RR), 256, 0, stream>>>(W_upd, wt_upd, HD, HD);

    // ---- CSR build + degree-ordered schedule ----
    hipMemsetAsync(cnt, 0, NN * sizeof(int), stream);
    hipMemsetAsync(dbin, 0, 64 * sizeof(int), stream);
    hist_kernel<<<EB, 256, 0, stream>>>(dst, cnt);
    scan1_kernel<<<NB, 256, 0, stream>>>(cnt, incl, bsum);
    scan2_kernel<<<1, 256, 0, stream>>>(bsum, NB);
    scan3_kernel<<<NB, 256, 0, stream>>>(cnt, incl, bsum, row_ptr, cnt);
    bucket_kernel<<<EB, 256, 0, stream>>>(src, dst, cnt, colsrc);
    dhist_kernel<<<NB, 256, 0, stream>>>(row_ptr, dbin);
    dscan_kernel<<<1, 64, 0, stream>>>(dbin, dcur);
    dscatter_kernel<<<NB, 256, 0, stream>>>(row_ptr, dcur, order);

    // ---- node pipeline ----
    const int MG = (NN + 63) / 64;
    const int GG = NPASS * GNB3;

    fused_kernel<MD, 0, false><<<MG, 256, 0, stream>>>(
        zb, wt_in, b_in, state,
        wt_msg, b_msg, msgb, nullptr, nullptr, nullptr, NN);

    for (int r = 0; r < RR - 1; r++) {
        gather_kernel<<<GG, 256, 0, stream>>>(row_ptr, order, colsrc,
                                              (const uint4*)msgb, (uint4*)aggb);
        fused_kernel<HD, 1, true><<<MG, 256, 0, stream>>>(
            aggb, wt_upd + (size_t)r * HD * HD, b_upd + (size_t)r * HD, state,
            wt_msg + (size_t)(r + 1) * HD * HD, b_msg + (size_t)(r + 1) * HD,
            msgb, nullptr, nullptr, nullptr, NN);
    }
    gather_kernel<<<GG, 256, 0, stream>>>(row_ptr, order, colsrc,
                                          (const uint4*)msgb, (uint4*)aggb);
    fused_kernel<HD, 2, true><<<MG, 256, 0, stream>>>(
        aggb, wt_upd + (size_t)(RR - 1) * HD * HD, b_upd + (size_t)(RR - 1) * HD, state,
        nullptr, nullptr, nullptr, W_out, b_out, node_out, NN);
}

// Round 7
// 417.928 us; speedup vs baseline: 1.9492x; 1.9492x over previous
//
#include <hip/hip_runtime.h>
#include <cstdint>

#define NN  50000
#define MD  64
#define HD  128
#define RR  4
#define FD  7
#define EE  800000
#define BG  32
#define NMX 512

typedef __attribute__((ext_vector_type(8))) short bf16x8;
typedef __attribute__((ext_vector_type(4))) float f32x4;

__device__ __forceinline__ unsigned short f2bf(float f) {
    unsigned u = __builtin_bit_cast(unsigned, f);
    u = (u + 0x7fffu + ((u >> 16) & 1u)) >> 16;
    return (unsigned short)u;
}
__device__ __forceinline__ float bflo(unsigned u) { return __builtin_bit_cast(float, u << 16); }
__device__ __forceinline__ float bfhi(unsigned u) { return __builtin_bit_cast(float, u & 0xffff0000u); }

__device__ __forceinline__ bf16x8 pack8(float4 a, float4 b) {
    bf16x8 r;
    r[0]=(short)f2bf(a.x); r[1]=(short)f2bf(a.y); r[2]=(short)f2bf(a.z); r[3]=(short)f2bf(a.w);
    r[4]=(short)f2bf(b.x); r[5]=(short)f2bf(b.y); r[6]=(short)f2bf(b.z); r[7]=(short)f2bf(b.w);
    return r;
}

// ---------------------------------------------------------------------------
// Edge logits via bf16 MFMA: C = Z Z^T + bias. 64x64 tile / 256-block.
// ---------------------------------------------------------------------------
__global__ __launch_bounds__(256) void edge_kernel(const unsigned short* __restrict__ zdb,
                                                   const float* __restrict__ bias,
                                                   float* __restrict__ out) {
    __shared__ float cstage[64][68];
    const int b  = blockIdx.z;
    const int tn = blockIdx.y * 64;
    const int tk = blockIdx.x * 64;
    const unsigned short* zb = zdb + (size_t)b * NMX * MD;
    const int tid = threadIdx.x, wave = tid >> 6, lane = tid & 63;
    const int l15 = lane & 15, k8 = (lane >> 4) * 8;

    const unsigned short* ap = zb + (size_t)(tn + wave * 16 + l15) * MD + k8;
    bf16x8 af0 = *(const bf16x8*)ap;
    bf16x8 af1 = *(const bf16x8*)(ap + 32);

    f32x4 acc[4];
    #pragma unroll
    for (int ct = 0; ct < 4; ct++) acc[ct] = (f32x4){0.f, 0.f, 0.f, 0.f};
    const unsigned short* bp = zb + (size_t)(tk + l15) * MD + k8;
    #pragma unroll
    for (int ct = 0; ct < 4; ct++) {
        bf16x8 b0 = *(const bf16x8*)(bp + (size_t)ct * 16 * MD);
        bf16x8 b1 = *(const bf16x8*)(bp + (size_t)ct * 16 * MD + 32);
        acc[ct] = __builtin_amdgcn_mfma_f32_16x16x32_bf16(af0, b0, acc[ct], 0, 0, 0);
        acc[ct] = __builtin_amdgcn_mfma_f32_16x16x32_bf16(af1, b1, acc[ct], 0, 0, 0);
    }
    #pragma unroll
    for (int ct = 0; ct < 4; ct++)
        #pragma unroll
        for (int i = 0; i < 4; i++)
            cstage[wave * 16 + (lane >> 4) * 4 + i][ct * 16 + l15] = acc[ct][i];
    __syncthreads();
    const float bi = bias[0];
    #pragma unroll
    for (int it = 0; it < 4; it++) {
        int f = tid + it * 256;
        int row = f >> 4, c4 = (f & 15) * 4;
        float4 v = *(const float4*)&cstage[row][c4];
        v.x += bi; v.y += bi; v.z += bi; v.w += bi;
        *(float4*)(out + ((size_t)b * NMX + tn + row) * NMX + tk + c4) = v;
    }
}

// ---------------------------------------------------------------------------
// Converters
// ---------------------------------------------------------------------------
__global__ __launch_bounds__(256) void cvt_kernel(const float* __restrict__ src,
                                                  unsigned short* __restrict__ dst,
                                                  int n4) {
    int i = blockIdx.x * 256 + threadIdx.x;
    if (i >= n4) return;
    float4 v = *(const float4*)(src + (size_t)i * 4);
    ushort4 o = {f2bf(v.x), f2bf(v.y), f2bf(v.z), f2bf(v.w)};
    *(ushort4*)(dst + (size_t)i * 4) = o;
}

__global__ __launch_bounds__(256) void tcvt_kernel(const float* __restrict__ src,
                                                   unsigned short* __restrict__ dst,
                                                   int K, int H) {
    int r = blockIdx.y;
    int i = blockIdx.x * 256 + threadIdx.x;
    if (i >= K * H) return;
    int k = i / H, h = i % H;
    float v = src[(size_t)r * K * H + i];
    dst[(size_t)r * K * H + (size_t)h * K + k] = f2bf(v);
}

// ---------------------------------------------------------------------------
// Fused MLP (two MFMA stages), flat [n][K] layouts.
// MODE 0: no addin, write state + msg.  MODE 1: addin=state_old, write state+msg.
// MODE 2: addin=state_old, node_out = state_new @ Wout + bout (no state write).
// ---------------------------------------------------------------------------
template <int K1, int MODE>
__global__ __launch_bounds__(256) void fused_kernel(
    const unsigned short* __restrict__ in,
    const unsigned short* __restrict__ Wt1,
    const float* __restrict__ b1,
    float* __restrict__ state,
    const unsigned short* __restrict__ Wt2,
    const float* __restrict__ b2,
    unsigned short* __restrict__ msgb,
    const float* __restrict__ Wout,
    const float* __restrict__ bout,
    float* __restrict__ node_out,
    int nrows)
{
    constexpr int KC1 = K1 / 32;
    __shared__ float cstage[64][132];
    __shared__ float sWout[MODE == 2 ? HD * FD : 1];
    const int tid = threadIdx.x, wave = tid >> 6, lane = tid & 63;
    const int l15 = lane & 15, k8 = (lane >> 4) * 8;
    const int rbase = blockIdx.x * 64;

    if constexpr (MODE == 2)
        for (int i = tid; i < HD * FD; i += 256) sWout[i] = Wout[i];

    // ---- stage 1 MFMA ----
    int rclamp = min(rbase + wave * 16 + l15, nrows - 1);
    bf16x8 af[KC1];
    #pragma unroll
    for (int c = 0; c < KC1; c++)
        af[c] = *(const bf16x8*)(in + (size_t)rclamp * K1 + (size_t)c * 32 + k8);
    f32x4 acc[8];
    #pragma unroll
    for (int ct = 0; ct < 8; ct++) acc[ct] = (f32x4){0.f, 0.f, 0.f, 0.f};
    const unsigned short* bp = Wt1 + (size_t)l15 * K1 + k8;
    #pragma unroll
    for (int ct = 0; ct < 8; ct++)
        #pragma unroll
        for (int c = 0; c < KC1; c++) {
            bf16x8 bf = *(const bf16x8*)(bp + (size_t)ct * 16 * K1 + c * 32);
            acc[ct] = __builtin_amdgcn_mfma_f32_16x16x32_bf16(af[c], bf, acc[ct], 0, 0, 0);
        }
    #pragma unroll
    for (int ct = 0; ct < 8; ct++)
        #pragma unroll
        for (int i = 0; i < 4; i++)
            cstage[wave * 16 + (lane >> 4) * 4 + i][ct * 16 + l15] = acc[ct][i];
    __syncthreads();

    // ---- epilogue 1: bias+relu (+state_old) -> state_new ----
    #pragma unroll
    for (int it = 0; it < 8; it++) {
        int f = tid + it * 256;
        int row = f >> 5, c4 = (f & 31) * 4;
        int grow = rbase + row;
        if (grow < nrows) {
            float4 v = *(const float4*)&cstage[row][c4];
            float4 bb = *(const float4*)(b1 + c4);
            v.x = fmaxf(v.x + bb.x, 0.f);
            v.y = fmaxf(v.y + bb.y, 0.f);
            v.z = fmaxf(v.z + bb.z, 0.f);
            v.w = fmaxf(v.w + bb.w, 0.f);
            if constexpr (MODE >= 1) {
                float4 so = *(const float4*)(state + (size_t)grow * HD + c4);
                v.x += so.x; v.y += so.y; v.z += so.z; v.w += so.w;
            }
            if constexpr (MODE <= 1)
                *(float4*)(state + (size_t)grow * HD + c4) = v;
            *(float4*)&cstage[row][c4] = v;
        }
    }
    __syncthreads();

    if constexpr (MODE <= 1) {
        // ---- stage 2 MFMA: A-frags from updated cstage ----
        bf16x8 af2[4];
        #pragma unroll
        for (int c = 0; c < 4; c++) {
            float4 u0 = *(const float4*)&cstage[wave * 16 + l15][c * 32 + k8];
            float4 u1 = *(const float4*)&cstage[wave * 16 + l15][c * 32 + k8 + 4];
            af2[c] = pack8(u0, u1);
        }
        f32x4 acc2[8];
        #pragma unroll
        for (int ct = 0; ct < 8; ct++) acc2[ct] = (f32x4){0.f, 0.f, 0.f, 0.f};
        const unsigned short* bp2 = Wt2 + (size_t)l15 * HD + k8;
        #pragma unroll
        for (int ct = 0; ct < 8; ct++)
            #pragma unroll
            for (int c = 0; c < 4; c++) {
                bf16x8 bf = *(const bf16x8*)(bp2 + (size_t)ct * 16 * HD + c * 32);
                acc2[ct] = __builtin_amdgcn_mfma_f32_16x16x32_bf16(af2[c], bf, acc2[ct], 0, 0, 0);
            }
        __syncthreads();
        #pragma unroll
        for (int ct = 0; ct < 8; ct++)
            #pragma unroll
            for (int i = 0; i < 4; i++)
                cstage[wave * 16 + (lane >> 4) * 4 + i][ct * 16 + l15] = acc2[ct][i];
        __syncthreads();
        #pragma unroll
        for (int it = 0; it < 8; it++) {
            int f = tid + it * 256;
            int row = f >> 5, c4 = (f & 31) * 4;
            int grow = rbase + row;
            if (grow < nrows) {
                float4 v = *(const float4*)&cstage[row][c4];
                float4 bb = *(const float4*)(b2 + c4);
                v.x = fmaxf(v.x + bb.x, 0.f);
                v.y = fmaxf(v.y + bb.y, 0.f);
                v.z = fmaxf(v.z + bb.z, 0.f);
                v.w = fmaxf(v.w + bb.w, 0.f);
                ushort4 o = {f2bf(v.x), f2bf(v.y), f2bf(v.z), f2bf(v.w)};
                *(ushort4*)(msgb + (size_t)grow * HD + c4) = o;
            }
        }
    } else {
        // ---- out projection: 64 rows x 7 cols, strided over 256 threads ----
        for (int i = tid; i < 64 * FD; i += 256) {
            int row = i / FD, ff = i - row * FD;
            int grow = rbase + row;
            if (grow < nrows) {
                float a = bout[ff];
                #pragma unroll 8
                for (int k = 0; k < HD; k++)
                    a += cstage[row][k] * sWout[k * FD + ff];
                node_out[(size_t)grow * FD + ff] = a;
            }
        }
    }
}

// ---------------------------------------------------------------------------
// CSR build
// ---------------------------------------------------------------------------
__global__ __launch_bounds__(256) void hist_kernel(const int* __restrict__ dst,
                                                   int* __restrict__ cnt) {
    int e = blockIdx.x * 256 + threadIdx.x;
    if (e < EE) atomicAdd(&cnt[dst[e]], 1);
}

__global__ __launch_bounds__(256) void scan1_kernel(const int* __restrict__ cnt,
                                                    int* __restrict__ incl,
                                                    int* __restrict__ bsum) {
    __shared__ int s[256];
    int i = blockIdx.x * 256 + threadIdx.x;
    int t = threadIdx.x;
    s[t] = (i < NN) ? cnt[i] : 0;
    __syncthreads();
    #pragma unroll
    for (int off = 1; off < 256; off <<= 1) {
        int x = (t >= off) ? s[t - off] : 0;
        __syncthreads();
        s[t] += x;
        __syncthreads();
    }
    if (i < NN) incl[i] = s[t];
    if (t == 255) bsum[blockIdx.x] = s[255];
}

__global__ __launch_bounds__(256) void scan2_kernel(int* __restrict__ bsum, int nb) {
    __shared__ int s[256];
    int t = threadIdx.x;
    int orig = (t < nb) ? bsum[t] : 0;
    s[t] = orig;
    __syncthreads();
    #pragma unroll
    for (int off = 1; off < 256; off <<= 1) {
        int x = (t >= off) ? s[t - off] : 0;
        __syncthreads();
        s[t] += x;
        __syncthreads();
    }
    if (t < nb) bsum[t] = s[t] - orig;
}

__global__ __launch_bounds__(256) void scan3_kernel(const int* __restrict__ cnt,
                                                    const int* __restrict__ incl,
                                                    const int* __restrict__ bsum,
                                                    int* __restrict__ row_ptr,
                                                    int* __restrict__ cursor) {
    int i = blockIdx.x * 256 + threadIdx.x;
    if (i < NN) {
        int ex = incl[i] - cnt[i] + bsum[blockIdx.x];
        row_ptr[i] = ex;
        cursor[i]  = ex;
        if (i == 0) row_ptr[NN] = EE;
    }
}

__global__ __launch_bounds__(256) void bucket_kernel(const int* __restrict__ src,
                                                     const int* __restrict__ dst,
                                                     int* __restrict__ cursor,
                                                     int* __restrict__ colsrc) {
    int e = blockIdx.x * 256 + threadIdx.x;
    if (e < EE) {
        int pos = atomicAdd(&cursor[dst[e]], 1);
        colsrc[pos] = src[e];
    }
}

// ---------------------------------------------------------------------------
// Gather v4: wave-per-node, 4 edges per load instruction.
// msg flat [node][16] uint4 (256 B rows). Lane l: edge-slot e=l>>4, quad q=l&15.
// One dwordx4 load covers 4 full rows; unroll x2 -> 2 KB in flight per wave.
// Cross-group reduce via shfl_xor(16,32); lanes 0-15 write coalesced 256 B.
// ---------------------------------------------------------------------------
__global__ __launch_bounds__(256) void gather_kernel(const int* __restrict__ rp,
                                                     const int* __restrict__ colsrc,
                                                     const uint4* __restrict__ msg4,
                                                     uint4* __restrict__ agg4) {
    int v = blockIdx.x * 4 + (threadIdx.x >> 6);
    if (v >= NN) return;
    const int lane = threadIdx.x & 63;
    const int e = lane >> 4, q = lane & 15;
    const int beg = rp[v], end = rp[v + 1];
    float a[8];
    #pragma unroll
    for (int i = 0; i < 8; i++) a[i] = 0.f;

    int j = beg;
    for (; j + 7 < end; j += 8) {
        int c0 = colsrc[j + e];
        int c1 = colsrc[j + 4 + e];
        uint4 u = msg4[(size_t)c0 * 16 + q];
        uint4 w = msg4[(size_t)c1 * 16 + q];
        a[0] += bflo(u.x); a[1] += bfhi(u.x);
        a[2] += bflo(u.y); a[3] += bfhi(u.y);
        a[4] += bflo(u.z); a[5] += bfhi(u.z);
        a[6] += bflo(u.w); a[7] += bfhi(u.w);
        a[0] += bflo(w.x); a[1] += bfhi(w.x);
        a[2] += bflo(w.y); a[3] += bfhi(w.y);
        a[4] += bflo(w.z); a[5] += bfhi(w.z);
        a[6] += bflo(w.w); a[7] += bfhi(w.w);
    }
    for (; j < end; j += 4) {
        if (j + e < end) {
            uint4 u = msg4[(size_t)colsrc[j + e] * 16 + q];
            a[0] += bflo(u.x); a[1] += bfhi(u.x);
            a[2] += bflo(u.y); a[3] += bfhi(u.y);
            a[4] += bflo(u.z); a[5] += bfhi(u.z);
            a[6] += bflo(u.w); a[7] += bfhi(u.w);
        }
    }
    // reduce across the 4 edge-groups (lanes q, q+16, q+32, q+48)
    #pragma unroll
    for (int i = 0; i < 8; i++) {
        a[i] += __shfl_xor(a[i], 16);
        a[i] += __shfl_xor(a[i], 32);
    }
    if (lane < 16) {
        uint4 o;
        o.x = (unsigned)f2bf(a[0]) | ((unsigned)f2bf(a[1]) << 16);
        o.y = (unsigned)f2bf(a[2]) | ((unsigned)f2bf(a[3]) << 16);
        o.z = (unsigned)f2bf(a[4]) | ((unsigned)f2bf(a[5]) << 16);
        o.w = (unsigned)f2bf(a[6]) | ((unsigned)f2bf(a[7]) << 16);
        agg4[(size_t)v * 16 + q] = o;
    }
}

extern "C" void kernel_launch(void* const* d_in, const int* in_sizes, int n_in,
                              void* d_out, int out_size, void* d_ws, size_t ws_size,
                              hipStream_t stream) {
    const float* z          = (const float*)d_in[0];
    const int*   edge_index = (const int*)  d_in[1];
    const float* z_dense    = (const float*)d_in[2];
    const float* bias       = (const float*)d_in[3];
    const float* W_in       = (const float*)d_in[4];
    const float* b_in       = (const float*)d_in[5];
    const float* W_msg      = (const float*)d_in[6];
    const float* b_msg      = (const float*)d_in[7];
    const float* W_upd      = (const float*)d_in[8];
    const float* b_upd      = (const float*)d_in[9];
    const float* W_out      = (const float*)d_in[10];
    const float* b_out      = (const float*)d_in[11];

    float* out      = (float*)d_out;
    float* edge_out = out;
    float* node_out = out + (size_t)BG * NMX * NMX;

    // ---- workspace (flat layouts) ----
    char* p = (char*)d_ws;
    float* state = (float*)p;                     p += (size_t)NN * HD * 4;
    unsigned short* msgb   = (unsigned short*)p;  p += (size_t)NN * HD * 2;
    unsigned short* aggb   = (unsigned short*)p;  p += (size_t)NN * HD * 2;
    unsigned short* zb     = (unsigned short*)p;  p += (size_t)NN * MD * 2;
    unsigned short* zdb    = (unsigned short*)p;  p += (size_t)BG * NMX * MD * 2;
    unsigned short* wt_in  = (unsigned short*)p;  p += (size_t)HD * MD * 2;
    unsigned short* wt_msg = (unsigned short*)p;  p += (size_t)RR * HD * HD * 2;
    unsigned short* wt_upd = (unsigned short*)p;  p += (size_t)RR * HD * HD * 2;
    int* cnt     = (int*)p;                       p += (size_t)NN * 4;
    int* incl    = (int*)p;                       p += (size_t)NN * 4;
    int* row_ptr = (int*)p;                       p += (size_t)(NN + 1) * 4;
    int* colsrc  = (int*)p;                       p += (size_t)EE * 4;
    int* bsum    = (int*)p;

    const int* src = edge_index;
    const int* dst = edge_index + EE;
    const int NB = (NN + 255) / 256;
    const int EB = (EE + 255) / 256;

    // ---- edge path ----
    cvt_kernel<<<(BG * NMX * MD / 4 + 255) / 256, 256, 0, stream>>>(
        z_dense, zdb, BG * NMX * MD / 4);
    dim3 eg(NMX / 64, NMX / 64, BG);
    edge_kernel<<<eg, 256, 0, stream>>>(zdb, bias, edge_out);

    // ---- conversions ----
    cvt_kernel<<<(NN * MD / 4 + 255) / 256, 256, 0, stream>>>(z, zb, NN * MD / 4);
    tcvt_kernel<<<dim3((MD * HD + 255) / 256, 1), 256, 0, stream>>>(W_in, wt_in, MD, HD);
    tcvt_kernel<<<dim3((HD * HD + 255) / 256, RR), 256, 0, stream>>>(W_msg, wt_msg, HD, HD);
    tcvt_kernel<<<dim3((HD * HD + 255) / 256, RR), 256, 0, stream>>>(W_upd, wt_upd, HD, HD);

    // ---- CSR build ----
    hipMemsetAsync(cnt, 0, NN * sizeof(int), stream);
    hist_kernel<<<EB, 256, 0, stream>>>(dst, cnt);
    scan1_kernel<<<NB, 256, 0, stream>>>(cnt, incl, bsum);
    scan2_kernel<<<1, 256, 0, stream>>>(bsum, NB);
    scan3_kernel<<<NB, 256, 0, stream>>>(cnt, incl, bsum, row_ptr, cnt);
    bucket_kernel<<<EB, 256, 0, stream>>>(src, dst, cnt, colsrc);

    // ---- node pipeline ----
    const int MG = (NN + 63) / 64;
    const int GG = (NN + 3) / 4;

    fused_kernel<MD, 0><<<MG, 256, 0, stream>>>(
        zb, wt_in, b_in, state,
        wt_msg, b_msg, msgb, nullptr, nullptr, nullptr, NN);

    for (int r = 0; r < RR - 1; r++) {
        gather_kernel<<<GG, 256, 0, stream>>>(row_ptr, colsrc,
                                              (const uint4*)msgb, (uint4*)aggb);
        fused_kernel<HD, 1><<<MG, 256, 0, stream>>>(
            aggb, wt_upd + (size_t)r * HD * HD, b_upd + (size_t)r * HD, state,
            wt_msg + (size_t)(r + 1) * HD * HD, b_msg + (size_t)(r + 1) * HD,
            msgb, nullptr, nullptr, nullptr, NN);
    }
    gather_kernel<<<GG, 256, 0, stream>>>(row_ptr, colsrc,
                                          (const uint4*)msgb, (uint4*)aggb);
    fused_kernel<HD, 2><<<MG, 256, 0, stream>>>(
        aggb, wt_upd + (size_t)(RR - 1) * HD * HD, b_upd + (size_t)(RR - 1) * HD, state,
        nullptr, nullptr, nullptr, W_out, b_out, node_out, NN);
}

// Round 8
// 359.638 us; speedup vs baseline: 2.2651x; 1.1621x over previous
//
#include <hip/hip_runtime.h>
#include <cstdint>

#define NN  50000
#define MD  64
#define HD  128
#define RR  4
#define FD  7
#define EE  800000
#define BG  32
#define NMX 512

// MSD bucket sort geometry
#define NH   196     // dst>>8 buckets (ceil(50000/256))
#define NBL  196     // P1 blocks (ceil(800000/4096))
#define BE   4096    // edges per P1 block
#define NS   (NH * NBL)          // 38416 scan entries
#define NSB  ((NS + 255) / 256)  // 151 scan chunks

typedef __attribute__((ext_vector_type(8))) short bf16x8;
typedef __attribute__((ext_vector_type(4))) float f32x4;

__device__ __forceinline__ unsigned short f2bf(float f) {
    unsigned u = __builtin_bit_cast(unsigned, f);
    u = (u + 0x7fffu + ((u >> 16) & 1u)) >> 16;
    return (unsigned short)u;
}
__device__ __forceinline__ float bflo(unsigned u) { return __builtin_bit_cast(float, u << 16); }
__device__ __forceinline__ float bfhi(unsigned u) { return __builtin_bit_cast(float, u & 0xffff0000u); }

__device__ __forceinline__ bf16x8 pack8(float4 a, float4 b) {
    bf16x8 r;
    r[0]=(short)f2bf(a.x); r[1]=(short)f2bf(a.y); r[2]=(short)f2bf(a.z); r[3]=(short)f2bf(a.w);
    r[4]=(short)f2bf(b.x); r[5]=(short)f2bf(b.y); r[6]=(short)f2bf(b.z); r[7]=(short)f2bf(b.w);
    return r;
}

// ---------------------------------------------------------------------------
// Edge logits via bf16 MFMA: C = Z Z^T + bias. 64x64 tile / 256-block.
// ---------------------------------------------------------------------------
__global__ __launch_bounds__(256) void edge_kernel(const unsigned short* __restrict__ zdb,
                                                   const float* __restrict__ bias,
                                                   float* __restrict__ out) {
    __shared__ float cstage[64][68];
    const int b  = blockIdx.z;
    const int tn = blockIdx.y * 64;
    const int tk = blockIdx.x * 64;
    const unsigned short* zb = zdb + (size_t)b * NMX * MD;
    const int tid = threadIdx.x, wave = tid >> 6, lane = tid & 63;
    const int l15 = lane & 15, k8 = (lane >> 4) * 8;

    const unsigned short* ap = zb + (size_t)(tn + wave * 16 + l15) * MD + k8;
    bf16x8 af0 = *(const bf16x8*)ap;
    bf16x8 af1 = *(const bf16x8*)(ap + 32);

    f32x4 acc[4];
    #pragma unroll
    for (int ct = 0; ct < 4; ct++) acc[ct] = (f32x4){0.f, 0.f, 0.f, 0.f};
    const unsigned short* bp = zb + (size_t)(tk + l15) * MD + k8;
    #pragma unroll
    for (int ct = 0; ct < 4; ct++) {
        bf16x8 b0 = *(const bf16x8*)(bp + (size_t)ct * 16 * MD);
        bf16x8 b1 = *(const bf16x8*)(bp + (size_t)ct * 16 * MD + 32);
        acc[ct] = __builtin_amdgcn_mfma_f32_16x16x32_bf16(af0, b0, acc[ct], 0, 0, 0);
        acc[ct] = __builtin_amdgcn_mfma_f32_16x16x32_bf16(af1, b1, acc[ct], 0, 0, 0);
    }
    #pragma unroll
    for (int ct = 0; ct < 4; ct++)
        #pragma unroll
        for (int i = 0; i < 4; i++)
            cstage[wave * 16 + (lane >> 4) * 4 + i][ct * 16 + l15] = acc[ct][i];
    __syncthreads();
    const float bi = bias[0];
    #pragma unroll
    for (int it = 0; it < 4; it++) {
        int f = tid + it * 256;
        int row = f >> 4, c4 = (f & 15) * 4;
        float4 v = *(const float4*)&cstage[row][c4];
        v.x += bi; v.y += bi; v.z += bi; v.w += bi;
        *(float4*)(out + ((size_t)b * NMX + tn + row) * NMX + tk + c4) = v;
    }
}

// ---------------------------------------------------------------------------
// Converters
// ---------------------------------------------------------------------------
__global__ __launch_bounds__(256) void cvt_kernel(const float* __restrict__ src,
                                                  unsigned short* __restrict__ dst,
                                                  int n4) {
    int i = blockIdx.x * 256 + threadIdx.x;
    if (i >= n4) return;
    float4 v = *(const float4*)(src + (size_t)i * 4);
    ushort4 o = {f2bf(v.x), f2bf(v.y), f2bf(v.z), f2bf(v.w)};
    *(ushort4*)(dst + (size_t)i * 4) = o;
}

__global__ __launch_bounds__(256) void tcvt_kernel(const float* __restrict__ src,
                                                   unsigned short* __restrict__ dst,
                                                   int K, int H) {
    int r = blockIdx.y;
    int i = blockIdx.x * 256 + threadIdx.x;
    if (i >= K * H) return;
    int k = i / H, h = i % H;
    float v = src[(size_t)r * K * H + i];
    dst[(size_t)r * K * H + (size_t)h * K + k] = f2bf(v);
}

// ---------------------------------------------------------------------------
// Fused MLP (two MFMA stages), flat [n][K] layouts.
// ---------------------------------------------------------------------------
template <int K1, int MODE>
__global__ __launch_bounds__(256) void fused_kernel(
    const unsigned short* __restrict__ in,
    const unsigned short* __restrict__ Wt1,
    const float* __restrict__ b1,
    float* __restrict__ state,
    const unsigned short* __restrict__ Wt2,
    const float* __restrict__ b2,
    unsigned short* __restrict__ msgb,
    const float* __restrict__ Wout,
    const float* __restrict__ bout,
    float* __restrict__ node_out,
    int nrows)
{
    constexpr int KC1 = K1 / 32;
    __shared__ float cstage[64][132];
    __shared__ float sWout[MODE == 2 ? HD * FD : 1];
    const int tid = threadIdx.x, wave = tid >> 6, lane = tid & 63;
    const int l15 = lane & 15, k8 = (lane >> 4) * 8;
    const int rbase = blockIdx.x * 64;

    if constexpr (MODE == 2)
        for (int i = tid; i < HD * FD; i += 256) sWout[i] = Wout[i];

    // ---- stage 1 MFMA ----
    int rclamp = min(rbase + wave * 16 + l15, nrows - 1);
    bf16x8 af[KC1];
    #pragma unroll
    for (int c = 0; c < KC1; c++)
        af[c] = *(const bf16x8*)(in + (size_t)rclamp * K1 + (size_t)c * 32 + k8);
    f32x4 acc[8];
    #pragma unroll
    for (int ct = 0; ct < 8; ct++) acc[ct] = (f32x4){0.f, 0.f, 0.f, 0.f};
    const unsigned short* bp = Wt1 + (size_t)l15 * K1 + k8;
    #pragma unroll
    for (int ct = 0; ct < 8; ct++)
        #pragma unroll
        for (int c = 0; c < KC1; c++) {
            bf16x8 bf = *(const bf16x8*)(bp + (size_t)ct * 16 * K1 + c * 32);
            acc[ct] = __builtin_amdgcn_mfma_f32_16x16x32_bf16(af[c], bf, acc[ct], 0, 0, 0);
        }
    #pragma unroll
    for (int ct = 0; ct < 8; ct++)
        #pragma unroll
        for (int i = 0; i < 4; i++)
            cstage[wave * 16 + (lane >> 4) * 4 + i][ct * 16 + l15] = acc[ct][i];
    __syncthreads();

    // ---- epilogue 1: bias+relu (+state_old) -> state_new ----
    #pragma unroll
    for (int it = 0; it < 8; it++) {
        int f = tid + it * 256;
        int row = f >> 5, c4 = (f & 31) * 4;
        int grow = rbase + row;
        if (grow < nrows) {
            float4 v = *(const float4*)&cstage[row][c4];
            float4 bb = *(const float4*)(b1 + c4);
            v.x = fmaxf(v.x + bb.x, 0.f);
            v.y = fmaxf(v.y + bb.y, 0.f);
            v.z = fmaxf(v.z + bb.z, 0.f);
            v.w = fmaxf(v.w + bb.w, 0.f);
            if constexpr (MODE >= 1) {
                float4 so = *(const float4*)(state + (size_t)grow * HD + c4);
                v.x += so.x; v.y += so.y; v.z += so.z; v.w += so.w;
            }
            if constexpr (MODE <= 1)
                *(float4*)(state + (size_t)grow * HD + c4) = v;
            *(float4*)&cstage[row][c4] = v;
        }
    }
    __syncthreads();

    if constexpr (MODE <= 1) {
        // ---- stage 2 MFMA: A-frags from updated cstage ----
        bf16x8 af2[4];
        #pragma unroll
        for (int c = 0; c < 4; c++) {
            float4 u0 = *(const float4*)&cstage[wave * 16 + l15][c * 32 + k8];
            float4 u1 = *(const float4*)&cstage[wave * 16 + l15][c * 32 + k8 + 4];
            af2[c] = pack8(u0, u1);
        }
        f32x4 acc2[8];
        #pragma unroll
        for (int ct = 0; ct < 8; ct++) acc2[ct] = (f32x4){0.f, 0.f, 0.f, 0.f};
        const unsigned short* bp2 = Wt2 + (size_t)l15 * HD + k8;
        #pragma unroll
        for (int ct = 0; ct < 8; ct++)
            #pragma unroll
            for (int c = 0; c < 4; c++) {
                bf16x8 bf = *(const bf16x8*)(bp2 + (size_t)ct * 16 * HD + c * 32);
                acc2[ct] = __builtin_amdgcn_mfma_f32_16x16x32_bf16(af2[c], bf, acc2[ct], 0, 0, 0);
            }
        __syncthreads();
        #pragma unroll
        for (int ct = 0; ct < 8; ct++)
            #pragma unroll
            for (int i = 0; i < 4; i++)
                cstage[wave * 16 + (lane >> 4) * 4 + i][ct * 16 + l15] = acc2[ct][i];
        __syncthreads();
        #pragma unroll
        for (int it = 0; it < 8; it++) {
            int f = tid + it * 256;
            int row = f >> 5, c4 = (f & 31) * 4;
            int grow = rbase + row;
            if (grow < nrows) {
                float4 v = *(const float4*)&cstage[row][c4];
                float4 bb = *(const float4*)(b2 + c4);
                v.x = fmaxf(v.x + bb.x, 0.f);
                v.y = fmaxf(v.y + bb.y, 0.f);
                v.z = fmaxf(v.z + bb.z, 0.f);
                v.w = fmaxf(v.w + bb.w, 0.f);
                ushort4 o = {f2bf(v.x), f2bf(v.y), f2bf(v.z), f2bf(v.w)};
                *(ushort4*)(msgb + (size_t)grow * HD + c4) = o;
            }
        }
    } else {
        // ---- out projection: 64 rows x 7 cols, strided over 256 threads ----
        for (int i = tid; i < 64 * FD; i += 256) {
            int row = i / FD, ff = i - row * FD;
            int grow = rbase + row;
            if (grow < nrows) {
                float a = bout[ff];
                #pragma unroll 8
                for (int k = 0; k < HD; k++)
                    a += cstage[row][k] * sWout[k * FD + ff];
                node_out[(size_t)grow * FD + ff] = a;
            }
        }
    }
}

// ---------------------------------------------------------------------------
// CSR build via 2-phase MSD bucket sort — LDS atomics only.
// P1: bucket by h = dst>>8 into sorted[] (dst,src) pairs.
// ---------------------------------------------------------------------------
__global__ __launch_bounds__(256) void p1c_kernel(const int* __restrict__ dst,
                                                  int* __restrict__ bh) {
    __shared__ int h[NH];
    const int b = blockIdx.x;
    for (int i = threadIdx.x; i < NH; i += 256) h[i] = 0;
    __syncthreads();
    const int e0 = b * BE;
    for (int i = threadIdx.x; i < BE; i += 256) {
        int e = e0 + i;
        if (e < EE) atomicAdd(&h[dst[e] >> 8], 1);
    }
    __syncthreads();
    for (int i = threadIdx.x; i < NH; i += 256) bh[i * NBL + b] = h[i];
}

// generic 256-chunk inclusive scan (n elements), writes incl + per-chunk sums
__global__ __launch_bounds__(256) void scan1_kernel(const int* __restrict__ in,
                                                    int* __restrict__ incl,
                                                    int* __restrict__ bsum, int n) {
    __shared__ int s[256];
    int i = blockIdx.x * 256 + threadIdx.x;
    int t = threadIdx.x;
    s[t] = (i < n) ? in[i] : 0;
    __syncthreads();
    #pragma unroll
    for (int off = 1; off < 256; off <<= 1) {
        int x = (t >= off) ? s[t - off] : 0;
        __syncthreads();
        s[t] += x;
        __syncthreads();
    }
    if (i < n) incl[i] = s[t];
    if (t == 255) bsum[blockIdx.x] = s[255];
}

__global__ __launch_bounds__(256) void scan2_kernel(int* __restrict__ bsum, int nb) {
    __shared__ int s[256];
    int t = threadIdx.x;
    int orig = (t < nb) ? bsum[t] : 0;
    s[t] = orig;
    __syncthreads();
    #pragma unroll
    for (int off = 1; off < 256; off <<= 1) {
        int x = (t >= off) ? s[t - off] : 0;
        __syncthreads();
        s[t] += x;
        __syncthreads();
    }
    if (t < nb) bsum[t] = s[t] - orig;   // exclusive
}

__global__ __launch_bounds__(256) void scanex_kernel(const int* __restrict__ in,
                                                     const int* __restrict__ incl,
                                                     const int* __restrict__ bsum,
                                                     int* __restrict__ ex, int n) {
    int i = blockIdx.x * 256 + threadIdx.x;
    if (i < n) ex[i] = incl[i] - in[i] + bsum[blockIdx.x];
}

__global__ __launch_bounds__(256) void p1s_kernel(const int* __restrict__ src,
                                                  const int* __restrict__ dst,
                                                  const int* __restrict__ ex,
                                                  int2* __restrict__ sorted) {
    __shared__ int cur[NH];
    const int b = blockIdx.x;
    for (int i = threadIdx.x; i < NH; i += 256) cur[i] = ex[i * NBL + b];
    __syncthreads();
    const int e0 = b * BE;
    for (int i = threadIdx.x; i < BE; i += 256) {
        int e = e0 + i;
        if (e < EE) {
            int d = dst[e];
            int pos = atomicAdd(&cur[d >> 8], 1);
            sorted[pos] = make_int2(d, src[e]);
        }
    }
}

// P2: one block per bucket; LDS hist+scan -> row_ptr, LDS cursors -> colsrc.
__global__ __launch_bounds__(256) void p2_kernel(const int2* __restrict__ sorted,
                                                 const int* __restrict__ ex,
                                                 int* __restrict__ row_ptr,
                                                 int* __restrict__ colsrc) {
    __shared__ int hist[256];
    __shared__ int scanb[256];
    __shared__ int cur[256];
    const int h = blockIdx.x;
    const int t = threadIdx.x;
    const int base = ex[h * NBL];
    const int endp = (h == NH - 1) ? EE : ex[(h + 1) * NBL];
    const int cnt  = endp - base;
    hist[t] = 0;
    __syncthreads();
    for (int i = t; i < cnt; i += 256)
        atomicAdd(&hist[sorted[base + i].x & 255], 1);
    __syncthreads();
    scanb[t] = hist[t];
    __syncthreads();
    #pragma unroll
    for (int off = 1; off < 256; off <<= 1) {
        int x = (t >= off) ? scanb[t - off] : 0;
        __syncthreads();
        scanb[t] += x;
        __syncthreads();
    }
    int excl = scanb[t] - hist[t];
    cur[t] = excl;
    int v = h * 256 + t;
    if (v < NN) row_ptr[v] = base + excl;
    if (h == NH - 1 && t == 0) row_ptr[NN] = EE;
    __syncthreads();
    for (int i = t; i < cnt; i += 256) {
        int2 pr = sorted[base + i];
        int pos = base + atomicAdd(&cur[pr.x & 255], 1);
        colsrc[pos] = pr.y;
    }
}

// ---------------------------------------------------------------------------
// Gather v4: wave-per-node, 4 edges per load instruction.
// ---------------------------------------------------------------------------
__global__ __launch_bounds__(256) void gather_kernel(const int* __restrict__ rp,
                                                     const int* __restrict__ colsrc,
                                                     const uint4* __restrict__ msg4,
                                                     uint4* __restrict__ agg4) {
    int v = blockIdx.x * 4 + (threadIdx.x >> 6);
    if (v >= NN) return;
    const int lane = threadIdx.x & 63;
    const int e = lane >> 4, q = lane & 15;
    const int beg = rp[v], end = rp[v + 1];
    float a[8];
    #pragma unroll
    for (int i = 0; i < 8; i++) a[i] = 0.f;

    int j = beg;
    for (; j + 7 < end; j += 8) {
        int c0 = colsrc[j + e];
        int c1 = colsrc[j + 4 + e];
        uint4 u = msg4[(size_t)c0 * 16 + q];
        uint4 w = msg4[(size_t)c1 * 16 + q];
        a[0] += bflo(u.x); a[1] += bfhi(u.x);
        a[2] += bflo(u.y); a[3] += bfhi(u.y);
        a[4] += bflo(u.z); a[5] += bfhi(u.z);
        a[6] += bflo(u.w); a[7] += bfhi(u.w);
        a[0] += bflo(w.x); a[1] += bfhi(w.x);
        a[2] += bflo(w.y); a[3] += bfhi(w.y);
        a[4] += bflo(w.z); a[5] += bfhi(w.z);
        a[6] += bflo(w.w); a[7] += bfhi(w.w);
    }
    for (; j < end; j += 4) {
        if (j + e < end) {
            uint4 u = msg4[(size_t)colsrc[j + e] * 16 + q];
            a[0] += bflo(u.x); a[1] += bfhi(u.x);
            a[2] += bflo(u.y); a[3] += bfhi(u.y);
            a[4] += bflo(u.z); a[5] += bfhi(u.z);
            a[6] += bflo(u.w); a[7] += bfhi(u.w);
        }
    }
    #pragma unroll
    for (int i = 0; i < 8; i++) {
        a[i] += __shfl_xor(a[i], 16);
        a[i] += __shfl_xor(a[i], 32);
    }
    if (lane < 16) {
        uint4 o;
        o.x = (unsigned)f2bf(a[0]) | ((unsigned)f2bf(a[1]) << 16);
        o.y = (unsigned)f2bf(a[2]) | ((unsigned)f2bf(a[3]) << 16);
        o.z = (unsigned)f2bf(a[4]) | ((unsigned)f2bf(a[5]) << 16);
        o.w = (unsigned)f2bf(a[6]) | ((unsigned)f2bf(a[7]) << 16);
        agg4[(size_t)v * 16 + q] = o;
    }
}

extern "C" void kernel_launch(void* const* d_in, const int* in_sizes, int n_in,
                              void* d_out, int out_size, void* d_ws, size_t ws_size,
                              hipStream_t stream) {
    const float* z          = (const float*)d_in[0];
    const int*   edge_index = (const int*)  d_in[1];
    const float* z_dense    = (const float*)d_in[2];
    const float* bias       = (const float*)d_in[3];
    const float* W_in       = (const float*)d_in[4];
    const float* b_in       = (const float*)d_in[5];
    const float* W_msg      = (const float*)d_in[6];
    const float* b_msg      = (const float*)d_in[7];
    const float* W_upd      = (const float*)d_in[8];
    const float* b_upd      = (const float*)d_in[9];
    const float* W_out      = (const float*)d_in[10];
    const float* b_out      = (const float*)d_in[11];

    float* out      = (float*)d_out;
    float* edge_out = out;
    float* node_out = out + (size_t)BG * NMX * NMX;

    // ---- workspace ----
    char* p = (char*)d_ws;
    float* state = (float*)p;                     p += (size_t)NN * HD * 4;
    unsigned short* msgb   = (unsigned short*)p;  p += (size_t)NN * HD * 2;
    unsigned short* aggb   = (unsigned short*)p;  p += (size_t)NN * HD * 2;
    unsigned short* zb     = (unsigned short*)p;  p += (size_t)NN * MD * 2;
    unsigned short* zdb    = (unsigned short*)p;  p += (size_t)BG * NMX * MD * 2;
    unsigned short* wt_in  = (unsigned short*)p;  p += (size_t)HD * MD * 2;
    unsigned short* wt_msg = (unsigned short*)p;  p += (size_t)RR * HD * HD * 2;
    unsigned short* wt_upd = (unsigned short*)p;  p += (size_t)RR * HD * HD * 2;
    int*  bh      = (int*)p;                      p += (size_t)NS * 4;
    int*  incl    = (int*)p;                      p += (size_t)NS * 4;
    int*  exsc    = (int*)p;                      p += (size_t)NS * 4;
    int*  row_ptr = (int*)p;                      p += (size_t)(NN + 1) * 4;
    int*  colsrc  = (int*)p;                      p += (size_t)EE * 4;
    int2* sorted  = (int2*)p;                     p += (size_t)EE * 8;
    int*  bsum    = (int*)p;

    const int* src = edge_index;
    const int* dst = edge_index + EE;

    // ---- edge path ----
    cvt_kernel<<<(BG * NMX * MD / 4 + 255) / 256, 256, 0, stream>>>(
        z_dense, zdb, BG * NMX * MD / 4);
    dim3 eg(NMX / 64, NMX / 64, BG);
    edge_kernel<<<eg, 256, 0, stream>>>(zdb, bias, edge_out);

    // ---- conversions ----
    cvt_kernel<<<(NN * MD / 4 + 255) / 256, 256, 0, stream>>>(z, zb, NN * MD / 4);
    tcvt_kernel<<<dim3((MD * HD + 255) / 256, 1), 256, 0, stream>>>(W_in, wt_in, MD, HD);
    tcvt_kernel<<<dim3((HD * HD + 255) / 256, RR), 256, 0, stream>>>(W_msg, wt_msg, HD, HD);
    tcvt_kernel<<<dim3((HD * HD + 255) / 256, RR), 256, 0, stream>>>(W_upd, wt_upd, HD, HD);

    // ---- CSR build: MSD bucket sort (LDS atomics only) ----
    p1c_kernel<<<NBL, 256, 0, stream>>>(dst, bh);
    scan1_kernel<<<NSB, 256, 0, stream>>>(bh, incl, bsum, NS);
    scan2_kernel<<<1, 256, 0, stream>>>(bsum, NSB);
    scanex_kernel<<<NSB, 256, 0, stream>>>(bh, incl, bsum, exsc, NS);
    p1s_kernel<<<NBL, 256, 0, stream>>>(src, dst, exsc, sorted);
    p2_kernel<<<NH, 256, 0, stream>>>(sorted, exsc, row_ptr, colsrc);

    // ---- node pipeline ----
    const int MG = (NN + 63) / 64;
    const int GG = (NN + 3) / 4;

    fused_kernel<MD, 0><<<MG, 256, 0, stream>>>(
        zb, wt_in, b_in, state,
        wt_msg, b_msg, msgb, nullptr, nullptr, nullptr, NN);

    for (int r = 0; r < RR - 1; r++) {
        gather_kernel<<<GG, 256, 0, stream>>>(row_ptr, colsrc,
                                              (const uint4*)msgb, (uint4*)aggb);
        fused_kernel<HD, 1><<<MG, 256, 0, stream>>>(
            aggb, wt_upd + (size_t)r * HD * HD, b_upd + (size_t)r * HD, state,
            wt_msg + (size_t)(r + 1) * HD * HD, b_msg + (size_t)(r + 1) * HD,
            msgb, nullptr, nullptr, nullptr, NN);
    }
    gather_kernel<<<GG, 256, 0, stream>>>(row_ptr, colsrc,
                                          (const uint4*)msgb, (uint4*)aggb);
    fused_kernel<HD, 2><<<MG, 256, 0, stream>>>(
        aggb, wt_upd + (size_t)(RR - 1) * HD * HD, b_upd + (size_t)(RR - 1) * HD, state,
        nullptr, nullptr, nullptr, W_out, b_out, node_out, NN);
}